// Round 4
// baseline (52.421 us; speedup 1.0000x reference)
//
#include <hip/hip_runtime.h>
#include <math.h>

#define B 8
#define G 64
#define S 256
#define DIM 41
#define ET 128
#define H 8
#define EK 16
#define NH 127
#define HD (H*DIM)   // 328
#define VROW 44      // padded value row (floats)
#define SEROW 12     // padded seT row (floats)

// ---------------- K1 "prep": kproj->kpT4, qproj, embitsT (d-major bits) ----------------
// grid 1792 x 256:
//   [0,1024): kproj, 2 rows each; [1024,1280): qproj, 2 rows each;
//   [1280,1792): embitsT per (b,g) with mask staged via LDS (coalesced)
__global__ __launch_bounds__(256) void prep_kernel(const float* __restrict__ key,
                                                   const float* __restrict__ Wk,
                                                   const float* __restrict__ bk,
                                                   const float* __restrict__ query,
                                                   const float* __restrict__ Wq,
                                                   const float* __restrict__ bq,
                                                   const float* __restrict__ mask,
                                                   const float* __restrict__ qt,
                                                   const float* __restrict__ tt,
                                                   const float* __restrict__ stride_in,
                                                   const float* __restrict__ Wr,
                                                   const float* __restrict__ br,
                                                   float* __restrict__ kpT,
                                                   float* __restrict__ qp,
                                                   unsigned int* __restrict__ embitsT) {
    __shared__ float smem[5248 + 64];   // 128 mask rows (128*41) + strd
    const int bid = blockIdx.x;
    const int tid = threadIdx.x;

    if (bid < 1024) {
        // ---- kproj: rows bid*2, bid*2+1 -> kpT float4 layout [b][j>>2][s][j&3]
        float* k0 = smem;
        float* k1 = smem + 48;
        const int half = tid >> 7;
        const int j = tid & 127;
        const int row = bid * 2 + half;
        if (j < DIM) (half ? k1 : k0)[j] = key[row * DIM + j];
        __syncthreads();
        const float* kr = half ? k1 : k0;
        float acc = bk[j];
#pragma unroll
        for (int i = 0; i < DIM; ++i) acc = fmaf(kr[i], Wk[i * ET + j], acc);
        const int b = row >> 8, s = row & 255;
        kpT[b * 32768 + (j >> 2) * 1024 + s * 4 + (j & 3)] = acc;
    } else if (bid < 1280) {
        // ---- qproj
        float* qlds = smem;             // [2][128]
        const int base = (bid - 1024) * 2;
        qlds[tid] = query[base * ET + tid];
        __syncthreads();
        const int half = tid >> 7;
        const int j = tid & 127;
        const float* qr = qlds + half * 128;
        float a0 = 0.f, a1 = 0.f, a2 = 0.f, a3 = 0.f;
#pragma unroll 8
        for (int i = 0; i < ET; i += 4) {
            a0 = fmaf(qr[i + 0], Wq[(i + 0) * ET + j], a0);
            a1 = fmaf(qr[i + 1], Wq[(i + 1) * ET + j], a1);
            a2 = fmaf(qr[i + 2], Wq[(i + 2) * ET + j], a2);
            a3 = fmaf(qr[i + 3], Wq[(i + 3) * ET + j], a3);
        }
        qp[(base + half) * ET + j] = bq[j] + ((a0 + a1) + (a2 + a3));
    } else {
        // ---- embitsT per (b,g): bit(s,d) = window & mask, d-major words:
        // embitsT[bg*328 + d*8 + (s>>5)], bit (s&31)
        float* mlds = smem;
        float* strd = smem + 5248;
        const int bg = bid - 1280;
        const int b = bg >> 6, g = bg & 63;
        if (tid < DIM) {
            float a = br[tid];
            for (int i = 0; i < DIM; ++i) a = fmaf(stride_in[i], Wr[i * DIM + tid], a);
            strd[tid] = 1.0f / (1.0f + expf(-a));
        }
        __syncthreads();
        const float qtg = qt[g];
        for (int rr = 0; rr < 2; ++rr) {
            // stage 128 mask rows coalesced
            for (int idx = tid; idx < 5248; idx += 256)
                mlds[idx] = mask[(size_t)b * S * DIM + rr * 5248 + idx];
            __syncthreads();
            if (tid < 128) {
                const int s = rr * 128 + tid;
                const float t = tt[b * S + s];
                const int wv = tid >> 6;          // wave within this half
                const int w = rr * 2 + wv;        // word-pair index 0..3
                unsigned int* op = embitsT + (size_t)bg * (DIM * 8) + w * 2;
#pragma unroll
                for (int d = 0; d < DIM; ++d) {
                    const float sd = strd[d];
                    const int ok = (t >= qtg - sd) & (t <= qtg + sd) & (mlds[tid * DIM + d] != 0.0f);
                    const unsigned long long bal = __ballot(ok);
                    if ((tid & 63) == 0) {
                        op[d * 8 + 0] = (unsigned int)bal;
                        op[d * 8 + 1] = (unsigned int)(bal >> 32);
                    }
                }
            }
            __syncthreads();
        }
    }
}

// ---------------- K2 "main": scores + softmax + masked PV + outproj, per (b,g) ----------------
__global__ __launch_bounds__(384) void main_kernel(const float* __restrict__ kpT,
                                                   const float* __restrict__ qp,
                                                   const unsigned int* __restrict__ embitsT,
                                                   const float* __restrict__ value,
                                                   const float* __restrict__ Wo,
                                                   const float* __restrict__ bo,
                                                   float* __restrict__ out) {
    __shared__ float vbuf[S * VROW];        // 45056B; aliased as partial buffers later
    __shared__ float seT[S][SEROW];         // e values, [s][h], padded row
    __shared__ float qv[ET];
    __shared__ float xrow[HD];
    __shared__ float po[3][128];
    __shared__ float wmax[4][8];
    __shared__ float Mb[8];

    const int bg = blockIdx.x;
    const int b = bg >> 6;
    const int tid = threadIdx.x;

    // weighted-phase thread mapping: tid = hh*176 + sc*11 + d4  (352 active)
    const int hh = tid / 176;               // 0/1 -> heads hh*4..+3
    const int rem = tid - hh * 176;
    const int sc = rem / 11;                // s-chunk 0..15 (16 s each)
    const int d4 = rem - sc * 11;           // d-quad 0..10
    unsigned int wd0 = 0, wd1 = 0, wd2 = 0, wd3 = 0;
    if (tid < 352) {
        const unsigned int* eb = embitsT + (size_t)bg * (DIM * 8) + (sc >> 1);
        const int d0 = d4 * 4;
        wd0 = (d0 + 0 < DIM) ? eb[(d0 + 0) * 8] : 0u;
        wd1 = (d0 + 1 < DIM) ? eb[(d0 + 1) * 8] : 0u;
        wd2 = (d0 + 2 < DIM) ? eb[(d0 + 2) * 8] : 0u;
        wd3 = (d0 + 3 < DIM) ? eb[(d0 + 3) * 8] : 0u;
    }

    if (tid < ET) qv[tid] = qp[(size_t)bg * ET + tid];
    // stage value padded to VROW (zeros in pad)
    for (int q = tid; q < S * 11; q += 384) {
        const int s = q / 11, dq = q - (q / 11) * 11;
        const float* vp = value + (size_t)b * S * DIM + s * DIM + dq * 4;
        float4 t;
        if (dq < 10) { t.x = vp[0]; t.y = vp[1]; t.z = vp[2]; t.w = vp[3]; }
        else         { t.x = vp[0]; t.y = 0.f;   t.z = 0.f;   t.w = 0.f;  }
        *reinterpret_cast<float4*>(&vbuf[s * VROW + dq * 4]) = t;
    }
    __syncthreads();

    // scores: s = tid (256 threads), 8 heads in registers
    float sc8[H];
    if (tid < S) {
        const float4* kb = reinterpret_cast<const float4*>(kpT) + (size_t)b * 8192 + tid;
#pragma unroll
        for (int h = 0; h < H; ++h) {
            float a = 0.f;
#pragma unroll
            for (int e4 = 0; e4 < 4; ++e4) {
                const float4 kv = kb[(h * 4 + e4) * 256];
                a = fmaf(qv[h * EK + e4 * 4 + 0], kv.x, a);
                a = fmaf(qv[h * EK + e4 * 4 + 1], kv.y, a);
                a = fmaf(qv[h * EK + e4 * 4 + 2], kv.z, a);
                a = fmaf(qv[h * EK + e4 * 4 + 3], kv.w, a);
            }
            sc8[h] = a * 0.25f;
        }
        // per-head wave max (in-register)
#pragma unroll
        for (int h = 0; h < H; ++h) {
            float m = sc8[h];
#pragma unroll
            for (int off = 32; off; off >>= 1) m = fmaxf(m, __shfl_xor(m, off));
            if ((tid & 63) == 0) wmax[tid >> 6][h] = m;
        }
    }
    __syncthreads();
    if (tid < H) Mb[tid] = fmaxf(fmaxf(wmax[0][tid], wmax[1][tid]),
                                 fmaxf(wmax[2][tid], wmax[3][tid]));
    __syncthreads();
    if (tid < S) {
        float4 e0, e1;
        e0.x = __expf(sc8[0] - Mb[0]); e0.y = __expf(sc8[1] - Mb[1]);
        e0.z = __expf(sc8[2] - Mb[2]); e0.w = __expf(sc8[3] - Mb[3]);
        e1.x = __expf(sc8[4] - Mb[4]); e1.y = __expf(sc8[5] - Mb[5]);
        e1.z = __expf(sc8[6] - Mb[6]); e1.w = __expf(sc8[7] - Mb[7]);
        *reinterpret_cast<float4*>(&seT[tid][0]) = e0;
        *reinterpret_cast<float4*>(&seT[tid][4]) = e1;
    }
    __syncthreads();

    // weighted phase: per thread 4 heads x 4 d x 16 s
    float aS[4][4] = {{0.f}};
    float aA[4][4] = {{0.f}};
    if (tid < 352) {
        const int sbase = sc * 16;
        const int shift0 = (sc & 1) * 16;
#pragma unroll
        for (int i = 0; i < 16; ++i) {
            const int s = sbase + i;
            const float4 v = *reinterpret_cast<const float4*>(&vbuf[s * VROW + d4 * 4]);
            const float4 e = *reinterpret_cast<const float4*>(&seT[s][hh * 4]);
            const unsigned sh = shift0 + i;
            const float b0 = ((wd0 >> sh) & 1u) ? 1.f : 0.f;
            const float b1 = ((wd1 >> sh) & 1u) ? 1.f : 0.f;
            const float b2 = ((wd2 >> sh) & 1u) ? 1.f : 0.f;
            const float b3 = ((wd3 >> sh) & 1u) ? 1.f : 0.f;
            const float vm0 = v.x * b0, vm1 = v.y * b1, vm2 = v.z * b2, vm3 = v.w * b3;
            const float ee[4] = {e.x, e.y, e.z, e.w};
#pragma unroll
            for (int a = 0; a < 4; ++a) {
                aA[a][0] = fmaf(ee[a], vm0, aA[a][0]);
                aA[a][1] = fmaf(ee[a], vm1, aA[a][1]);
                aA[a][2] = fmaf(ee[a], vm2, aA[a][2]);
                aA[a][3] = fmaf(ee[a], vm3, aA[a][3]);
                aS[a][0] = fmaf(ee[a], b0, aS[a][0]);
                aS[a][1] = fmaf(ee[a], b1, aS[a][1]);
                aS[a][2] = fmaf(ee[a], b2, aS[a][2]);
                aS[a][3] = fmaf(ee[a], b3, aS[a][3]);
            }
        }
    }
    __syncthreads();   // vbuf reads done; safe to alias

    float* pS = vbuf;               // [328][17]
    float* pA = vbuf + 328 * 17;    // total 2*328*17 = 11152 <= 11264
    if (tid < 352) {
#pragma unroll
        for (int a = 0; a < 4; ++a) {
#pragma unroll
            for (int j = 0; j < 4; ++j) {
                const int d = d4 * 4 + j;
                if (d < DIM) {
                    const int hd = (hh * 4 + a) * DIM + d;
                    pS[hd * 17 + sc] = aS[a][j];
                    pA[hd * 17 + sc] = aA[a][j];
                }
            }
        }
    }
    __syncthreads();

    if (tid < HD) {
        float Ss = 0.f, Aa = 0.f;
#pragma unroll
        for (int k = 0; k < 16; ++k) { Ss += pS[tid * 17 + k]; Aa += pA[tid * 17 + k]; }
        float r;
        if (Ss != 0.f) {
            r = Aa / Ss;
        } else {
            const int d = tid % DIM;    // all-masked: uniform softmax -> column mean
            float vs = 0.f;
            const float* vc = value + (size_t)b * S * DIM + d;
            for (int s2 = 0; s2 < S; ++s2) vs += vc[(size_t)s2 * DIM];
            r = vs * (1.0f / S);
        }
        xrow[tid] = r;
    }
    __syncthreads();

    // out-proj: 3 i-chunks (110,110,108), lanes n = tid&127
    {
        const int n = tid & 127, c = tid >> 7;
        const int i0 = c * 110, i1 = (c == 2) ? HD : (i0 + 110);
        if (n < NH) {
            float a0 = 0.f, a1 = 0.f;
            for (int i = i0; i < i1; i += 2) {
                a0 = fmaf(xrow[i],     Wo[(size_t)i * NH + n],       a0);
                a1 = fmaf(xrow[i + 1], Wo[(size_t)(i + 1) * NH + n], a1);
            }
            po[c][n] = a0 + a1;
        }
    }
    __syncthreads();
    if (tid < NH)
        out[(size_t)bg * NH + tid] = bo[tid] + ((po[0][tid] + po[1][tid]) + po[2][tid]);
}

extern "C" void kernel_launch(void* const* d_in, const int* in_sizes, int n_in,
                              void* d_out, int out_size, void* d_ws, size_t ws_size,
                              hipStream_t stream) {
    const float* query     = (const float*)d_in[0];
    const float* key       = (const float*)d_in[1];
    const float* value     = (const float*)d_in[2];
    const float* mask      = (const float*)d_in[3];
    const float* qt        = (const float*)d_in[4];
    const float* tt        = (const float*)d_in[5];
    const float* stride_in = (const float*)d_in[6];
    const float* Wq        = (const float*)d_in[7];
    const float* bq        = (const float*)d_in[8];
    const float* Wk        = (const float*)d_in[9];
    const float* bk        = (const float*)d_in[10];
    const float* Wo        = (const float*)d_in[11];
    const float* bo        = (const float*)d_in[12];
    const float* Wr        = (const float*)d_in[13];
    const float* br        = (const float*)d_in[14];
    float* out = (float*)d_out;

    float* kpT = (float*)d_ws;                                         // 262144 f32
    float* qp = kpT + (size_t)B * H * 4 * S * 4;                       // 65536 f32
    unsigned int* embitsT = (unsigned int*)(qp + (size_t)B * G * ET);  // B*G*DIM*8 u32

    prep_kernel<<<1792, 256, 0, stream>>>(key, Wk, bk, query, Wq, bq, mask, qt, tt,
                                          stride_in, Wr, br, kpT, qp, embitsT);
    main_kernel<<<B * G, 384, 0, stream>>>(kpT, qp, embitsT, value, Wo, bo, out);
}